// Round 2
// baseline (17836.549 us; speedup 1.0000x reference)
//
#include <hip/hip_runtime.h>
#include <hip/hip_bf16.h>

// ---------------- problem constants ----------------
constexpr int Bc  = 8;
constexpr int SPc = 1024;
constexpr int SFc = 1024;
constexpr int Sc  = 2048;   // SP + SF
constexpr int Dc  = 512;
constexpr int Lc  = 4;
constexpr int Hc  = 8;
constexpr int Wc  = 128;    // cluster window
constexpr int DHc = 64;     // head dim
constexpr int Cc  = 16;     // clusters
constexpr int FFc = 2048;
constexpr int Mrows = Bc * Sc;  // 16384

// ---------------- embed: h = [x | y] @ W_emb + b_emb (f64 accum) ----------------
__global__ __launch_bounds__(256) void embed_kernel(
    const float* __restrict__ px, const float* __restrict__ py,
    const float* __restrict__ fx, const float* __restrict__ We,
    const float* __restrict__ be, float* __restrict__ h)
{
  int i = blockIdx.x * 256 + threadIdx.x;       // over B*S*D
  int d  = i & 511;
  int bs = i >> 9;                               // b*S + s
  int s  = bs & (Sc - 1);
  int b  = bs >> 11;
  float x[7];
  if (s < SPc) {
    int r = b * SPc + s;
#pragma unroll
    for (int t = 0; t < 6; ++t) x[t] = px[r * 6 + t];
    x[6] = py[r];
  } else {
    int r = b * SFc + (s - SPc);
#pragma unroll
    for (int t = 0; t < 6; ++t) x[t] = fx[r * 6 + t];
    x[6] = py[b * SPc + SPc - 1];                // last observed y, repeated
  }
  double a = (double)be[d];
#pragma unroll
  for (int t = 0; t < 7; ++t) a = fma((double)x[t], (double)We[t * Dc + d], a);
  h[i] = (float)a;
}

// ---------------- row LayerNorm (D=512, block=256), f64 reduction ----------------
__global__ __launch_bounds__(256) void ln_kernel(
    const float* __restrict__ x, const float* __restrict__ g,
    const float* __restrict__ bb, float* __restrict__ o)
{
  int row = blockIdx.x;
  const float* xr = x + (size_t)row * Dc;
  float* orow = o + (size_t)row * Dc;
  int tid = threadIdx.x;
  float v0 = xr[tid], v1 = xr[tid + 256];
  double s = (double)v0 + (double)v1;
  double sq = (double)v0 * v0 + (double)v1 * v1;
  __shared__ double ra[4], rb[4];
  int lane = tid & 63, w = tid >> 6;
#pragma unroll
  for (int off = 32; off; off >>= 1) { s += __shfl_down(s, off); sq += __shfl_down(sq, off); }
  if (lane == 0) { ra[w] = s; rb[w] = sq; }
  __syncthreads();
  s  = ra[0] + ra[1] + ra[2] + ra[3];
  sq = rb[0] + rb[1] + rb[2] + rb[3];
  double m   = s * (1.0 / Dc);
  double var = sq * (1.0 / Dc) - m * m;
  double rs  = 1.0 / sqrt(var + 1e-5);
  orow[tid]       = (float)(((double)v0 - m) * rs * (double)g[tid]       + (double)bb[tid]);
  orow[tid + 256] = (float)(((double)v1 - m) * rs * (double)g[tid + 256] + (double)bb[tid + 256]);
}

// ---------------- tiled GEMM: C = A(MxK) @ B(KxN), f64 accumulate ----------------
__device__ __forceinline__ float gelu_tanh(float v) {
  float x3 = v * v * v;
  return 0.5f * v * (1.0f + tanhf(0.7978845608028654f * (v + 0.044715f * x3)));
}

template<bool BIAS, bool GELU_, bool RES>
__global__ __launch_bounds__(256) void gemm128(
    const float* __restrict__ A, const float* __restrict__ Bm,
    const float* __restrict__ bias, float* __restrict__ Cm,
    int N, int K)
{
  constexpr int BM = 128, BN = 128, BK = 16;
  __shared__ float As[BK][BM + 4];
  __shared__ float Bs[BK][BN + 4];
  const int tid = threadIdx.x;
  const int tx = tid & 15, ty = tid >> 4;
  const int nbn = N >> 7;
  const int bm = blockIdx.x / nbn, bn = blockIdx.x % nbn;
  const float* Ab = A + (size_t)bm * BM * K;
  const float* Bb = Bm + bn * BN;
  double acc[8][8] = {};

  for (int k0 = 0; k0 < K; k0 += BK) {
#pragma unroll
    for (int r = 0; r < 8; ++r) {
      int e = r * 256 + tid;
      int m = e >> 4, kk = e & 15;
      As[kk][m] = Ab[(size_t)m * K + k0 + kk];
    }
#pragma unroll
    for (int r = 0; r < 8; ++r) {
      int e = r * 256 + tid;
      int kk = e >> 7, n = e & 127;
      Bs[kk][n] = Bb[(size_t)(k0 + kk) * N + n];
    }
    __syncthreads();
#pragma unroll
    for (int kk = 0; kk < BK; ++kk) {
      float a[8], bf[8];
      *(float4*)&a[0]  = *(const float4*)&As[kk][ty * 8];
      *(float4*)&a[4]  = *(const float4*)&As[kk][ty * 8 + 4];
      *(float4*)&bf[0] = *(const float4*)&Bs[kk][tx * 8];
      *(float4*)&bf[4] = *(const float4*)&Bs[kk][tx * 8 + 4];
#pragma unroll
      for (int i = 0; i < 8; ++i)
#pragma unroll
        for (int j = 0; j < 8; ++j)
          acc[i][j] = fma((double)a[i], (double)bf[j], acc[i][j]);
    }
    __syncthreads();
  }
#pragma unroll
  for (int i = 0; i < 8; ++i) {
    int row = bm * BM + ty * 8 + i;
    float* crow = Cm + (size_t)row * N + bn * BN;
#pragma unroll
    for (int j = 0; j < 8; ++j) {
      double vd = acc[i][j];
      int col = tx * 8 + j;
      if (BIAS)  vd += (double)bias[bn * BN + col];
      float v = (float)vd;
      if (GELU_) v = gelu_tanh(v);
      if (RES)   v += crow[col];
      crow[col] = v;
    }
  }
}

// ---------------- routing scores (f64 accum): sc[b,h,c,s] = normalize(q).means ----------------
__global__ __launch_bounds__(256) void scores_kernel(
    const float* __restrict__ q, const float* __restrict__ means,
    float* __restrict__ sc)
{
  int gw   = blockIdx.x * 4 + (threadIdx.x >> 6);  // (b*S+s)*H + h
  int lane = threadIdx.x & 63;
  int h  = gw & 7;
  int bs = gw >> 3;
  int s  = bs & (Sc - 1);
  int b  = bs >> 11;
  float qv = q[(size_t)bs * Dc + h * DHc + lane];
  double sq = (double)qv * (double)qv;
#pragma unroll
  for (int off = 32; off; off >>= 1) sq += __shfl_xor(sq, off);
  double qn = (double)qv / sqrt(sq + 1e-8);
  double myval = 0.0;
#pragma unroll
  for (int c = 0; c < Cc; ++c) {
    double p = qn * (double)means[(h * Cc + c) * DHc + lane];
#pragma unroll
    for (int off = 32; off; off >>= 1) p += __shfl_xor(p, off);
    if (lane == c) myval = p;
  }
  if (lane < Cc)
    sc[(((size_t)b * Hc + h) * Cc + lane) * Sc + s] = (float)myval;
}

// ---------------- top-128 of 2048 via bitonic sort (descending) ----------------
__global__ __launch_bounds__(256) void topk_kernel(
    const float* __restrict__ sc, int* __restrict__ idx_out)
{
  __shared__ float sv[Sc];
  __shared__ int   si[Sc];
  int base = blockIdx.x * Sc;
  int tid = threadIdx.x;
  for (int i = tid; i < Sc; i += 256) { sv[i] = sc[base + i]; si[i] = i; }
  __syncthreads();
  for (int k = 2; k <= Sc; k <<= 1) {
    for (int j = k >> 1; j > 0; j >>= 1) {
      for (int i = tid; i < Sc; i += 256) {
        int ixj = i ^ j;
        if (ixj > i) {
          bool asc = (i & k) != 0;            // overall descending
          float a = sv[i], b2 = sv[ixj];
          if (asc ? (a > b2) : (a < b2)) {
            sv[i] = b2; sv[ixj] = a;
            int t = si[i]; si[i] = si[ixj]; si[ixj] = t;
          }
        }
      }
      __syncthreads();
    }
  }
  if (tid < Wc) idx_out[blockIdx.x * Wc + tid] = si[tid];
}

// ---------------- within-cluster attention (f64 math) + scatter-add ----------------
__global__ __launch_bounds__(128) void attn_kernel(
    const float* __restrict__ q, const float* __restrict__ k,
    const float* __restrict__ v, const int* __restrict__ iq,
    const int* __restrict__ ik, float* __restrict__ accum,
    float* __restrict__ cnt)
{
  __shared__ float ks[Wc][DHc];
  __shared__ float vs[Wc][DHc];
  __shared__ int iqs[Wc], iks[Wc];
  int blk = blockIdx.x;                 // (b*H + h)*C + c
  int tid = threadIdx.x;
  int bh = blk / Cc;
  int h = bh & 7, b = bh >> 3;
  iqs[tid] = iq[blk * Wc + tid];
  iks[tid] = ik[blk * Wc + tid];
  __syncthreads();
  for (int e = tid; e < Wc * DHc; e += 128) {
    int j = e >> 6, d = e & 63;
    size_t off = ((size_t)b * Sc + iks[j]) * Dc + h * DHc + d;
    ks[j][d] = k[off];
    vs[j][d] = v[off];
  }
  __syncthreads();

  size_t qoff = ((size_t)b * Sc + iqs[tid]) * Dc + h * DHc;
  float qr[DHc];
  const float4* q4 = (const float4*)(q + qoff);
#pragma unroll
  for (int d4 = 0; d4 < 16; ++d4) {
    float4 t = q4[d4];
    qr[4 * d4] = t.x; qr[4 * d4 + 1] = t.y; qr[4 * d4 + 2] = t.z; qr[4 * d4 + 3] = t.w;
  }
  double m = -1e300, lsum = 0.0;
  double acc[DHc];
#pragma unroll
  for (int d = 0; d < DHc; ++d) acc[d] = 0.0;

  for (int j = 0; j < Wc; ++j) {
    const float* krow = ks[j];
    double s = 0.0;
#pragma unroll
    for (int d = 0; d < DHc; ++d)
      s = fma((double)qr[d], (double)krow[d], s);
    s *= 0.125;                          // DH^-0.5
    double mn = fmax(m, s);
    double scale = exp(m - mn);
    double p = exp(s - mn);
    lsum = lsum * scale + p;
    const float* vrow = vs[j];
#pragma unroll
    for (int d = 0; d < DHc; ++d)
      acc[d] = fma(acc[d], scale, p * (double)vrow[d]);
    m = mn;
  }
  double inv = 1.0 / lsum;
  float* arow = accum + qoff;
#pragma unroll
  for (int d = 0; d < DHc; ++d) atomicAdd(&arow[d], (float)(acc[d] * inv));
  atomicAdd(&cnt[((size_t)b * Sc + iqs[tid]) * Hc + h], 1.0f);
}

// ---------------- divide by routing count ----------------
__global__ __launch_bounds__(256) void div_kernel(
    float* __restrict__ accum, const float* __restrict__ cnt)
{
  size_t i = (size_t)blockIdx.x * 256 + threadIdx.x;   // over B*S*D
  float c = cnt[i >> 6];                               // (b*S+s)*H + h
  accum[i] /= fmaxf(c, 1.0f);
}

// ---------------- final LN + heads (only future half), f64 ----------------
__global__ __launch_bounds__(256) void final_kernel(
    const float* __restrict__ h, const float* __restrict__ g,
    const float* __restrict__ be, const float* __restrict__ wm,
    const float* __restrict__ bm, const float* __restrict__ wsd,
    const float* __restrict__ bsd, float* __restrict__ out)
{
  int blk = blockIdx.x;                   // b*SF + sf
  int b = blk >> 10, sf = blk & 1023;
  const float* hr = h + ((size_t)b * Sc + SPc + sf) * Dc;
  int tid = threadIdx.x;
  float v0 = hr[tid], v1 = hr[tid + 256];
  double s = (double)v0 + (double)v1;
  double sq = (double)v0 * v0 + (double)v1 * v1;
  __shared__ double ra[4], rb[4];
  int lane = tid & 63, w = tid >> 6;
#pragma unroll
  for (int off = 32; off; off >>= 1) { s += __shfl_down(s, off); sq += __shfl_down(sq, off); }
  if (lane == 0) { ra[w] = s; rb[w] = sq; }
  __syncthreads();
  s  = ra[0] + ra[1] + ra[2] + ra[3];
  sq = rb[0] + rb[1] + rb[2] + rb[3];
  double m   = s * (1.0 / Dc);
  double var = sq * (1.0 / Dc) - m * m;
  double rs  = 1.0 / sqrt(var + 1e-5);
  double n0 = ((double)v0 - m) * rs * (double)g[tid]       + (double)be[tid];
  double n1 = ((double)v1 - m) * rs * (double)g[tid + 256] + (double)be[tid + 256];
  double d1 = n0 * (double)wm[tid]  + n1 * (double)wm[tid + 256];
  double d2 = n0 * (double)wsd[tid] + n1 * (double)wsd[tid + 256];
  __syncthreads();
#pragma unroll
  for (int off = 32; off; off >>= 1) { d1 += __shfl_down(d1, off); d2 += __shfl_down(d2, off); }
  if (lane == 0) { ra[w] = d1; rb[w] = d2; }
  __syncthreads();
  if (tid == 0) {
    double mean = ra[0] + ra[1] + ra[2] + ra[3] + (double)bm[0];
    double ls   = rb[0] + rb[1] + rb[2] + rb[3] + (double)bsd[0];
    double sp = fmax(ls, 0.0) + log1p(exp(-fabs(ls)));   // softplus, stable
    out[blk] = (float)mean;
    out[Bc * SFc + blk] = (float)(0.01 + 0.99 * sp);
  }
}

// ---------------- host orchestration ----------------
extern "C" void kernel_launch(void* const* d_in, const int* in_sizes, int n_in,
                              void* d_out, int out_size, void* d_ws, size_t ws_size,
                              hipStream_t stream) {
  (void)in_sizes; (void)n_in; (void)out_size; (void)ws_size;
  const float* past_x   = (const float*)d_in[0];
  const float* past_y   = (const float*)d_in[1];
  const float* future_x = (const float*)d_in[2];
  const float* W_emb    = (const float*)d_in[3];
  const float* b_emb    = (const float*)d_in[4];
  const float* ln1_g    = (const float*)d_in[5];
  const float* ln1_b    = (const float*)d_in[6];
  const float* Wq       = (const float*)d_in[7];
  const float* Wk       = (const float*)d_in[8];
  const float* Wv       = (const float*)d_in[9];
  const float* Wo       = (const float*)d_in[10];
  const float* means    = (const float*)d_in[11];
  const float* ln2_g    = (const float*)d_in[12];
  const float* ln2_b    = (const float*)d_in[13];
  const float* W1       = (const float*)d_in[14];
  const float* b1       = (const float*)d_in[15];
  const float* W2       = (const float*)d_in[16];
  const float* b2       = (const float*)d_in[17];
  const float* lnf_g    = (const float*)d_in[18];
  const float* lnf_b    = (const float*)d_in[19];
  const float* W_mean   = (const float*)d_in[20];
  const float* b_mean   = (const float*)d_in[21];
  const float* W_std    = (const float*)d_in[22];
  const float* b_std    = (const float*)d_in[23];

  const size_t BSD = (size_t)Bc * Sc * Dc;        // 8.39M floats
  float* h     = (float*)d_ws;                    // [BSD]
  float* lnbuf = h + BSD;                         // [BSD]
  float* qb    = lnbuf + BSD;                     // [BSD]
  float* kb    = qb + BSD;                        // [BSD]
  float* vb    = kb + BSD;                        // [BSD]
  float* accum = vb + BSD;                        // [BSD]
  float* mid   = qb;                              // [4*BSD] reuses q/k/v/accum (dead by FFN)
  float* scq   = accum + BSD;                     // [B*H*C*S]
  float* sck   = scq + (size_t)Bc * Hc * Cc * Sc; // [B*H*C*S]
  int*   iq    = (int*)(sck + (size_t)Bc * Hc * Cc * Sc);  // [B*H*C*W]
  int*   ik    = iq + Bc * Hc * Cc * Wc;                   // [B*H*C*W]
  float* cnt   = (float*)(ik + Bc * Hc * Cc * Wc);         // [B*S*H]

  embed_kernel<<<(int)(BSD / 256), 256, 0, stream>>>(past_x, past_y, future_x, W_emb, b_emb, h);

  for (int l = 0; l < Lc; ++l) {
    ln_kernel<<<Mrows, 256, 0, stream>>>(h, ln1_g + l * Dc, ln1_b + l * Dc, lnbuf);

    gemm128<false,false,false><<<(Mrows/128)*(Dc/128), 256, 0, stream>>>(
        lnbuf, Wq + (size_t)l * Dc * Dc, nullptr, qb, Dc, Dc);
    gemm128<false,false,false><<<(Mrows/128)*(Dc/128), 256, 0, stream>>>(
        lnbuf, Wk + (size_t)l * Dc * Dc, nullptr, kb, Dc, Dc);
    gemm128<false,false,false><<<(Mrows/128)*(Dc/128), 256, 0, stream>>>(
        lnbuf, Wv + (size_t)l * Dc * Dc, nullptr, vb, Dc, Dc);

    const float* mns = means + (size_t)l * Hc * Cc * DHc;
    scores_kernel<<<Bc * Sc * Hc / 4, 256, 0, stream>>>(qb, mns, scq);
    scores_kernel<<<Bc * Sc * Hc / 4, 256, 0, stream>>>(kb, mns, sck);
    topk_kernel<<<Bc * Hc * Cc, 256, 0, stream>>>(scq, iq);
    topk_kernel<<<Bc * Hc * Cc, 256, 0, stream>>>(sck, ik);

    hipMemsetAsync(accum, 0, BSD * sizeof(float), stream);
    hipMemsetAsync(cnt, 0, (size_t)Bc * Sc * Hc * sizeof(float), stream);

    attn_kernel<<<Bc * Hc * Cc, 128, 0, stream>>>(qb, kb, vb, iq, ik, accum, cnt);
    div_kernel<<<(int)(BSD / 256), 256, 0, stream>>>(accum, cnt);

    gemm128<false,false,true><<<(Mrows/128)*(Dc/128), 256, 0, stream>>>(
        accum, Wo + (size_t)l * Dc * Dc, nullptr, h, Dc, Dc);

    ln_kernel<<<Mrows, 256, 0, stream>>>(h, ln2_g + l * Dc, ln2_b + l * Dc, lnbuf);

    gemm128<true,true,false><<<(Mrows/128)*(FFc/128), 256, 0, stream>>>(
        lnbuf, W1 + (size_t)l * Dc * FFc, b1 + (size_t)l * FFc, mid, FFc, Dc);
    gemm128<true,false,true><<<(Mrows/128)*(Dc/128), 256, 0, stream>>>(
        mid, W2 + (size_t)l * FFc * Dc, b2 + (size_t)l * Dc, h, Dc, FFc);
  }

  final_kernel<<<Bc * SFc, 256, 0, stream>>>(h, lnf_g, lnf_b, W_mean, b_mean,
                                             W_std, b_std, (float*)d_out);
}

// Round 7
// 15210.530 us; speedup vs baseline: 1.1726x; 1.1726x over previous
//
#include <hip/hip_runtime.h>
#include <hip/hip_bf16.h>

// ---------------- problem constants ----------------
constexpr int Bc  = 8;
constexpr int SPc = 1024;
constexpr int SFc = 1024;
constexpr int Sc  = 2048;   // SP + SF
constexpr int Dc  = 512;
constexpr int Lc  = 4;
constexpr int Hc  = 8;
constexpr int Wc  = 128;    // cluster window
constexpr int DHc = 64;     // head dim
constexpr int Cc  = 16;     // clusters
constexpr int FFc = 2048;
constexpr int Mrows = Bc * Sc;  // 16384

typedef _Float16 half8 __attribute__((ext_vector_type(8)));
typedef _Float16 half4 __attribute__((ext_vector_type(4)));
typedef float    f32x4 __attribute__((ext_vector_type(4)));
typedef double   f64x4 __attribute__((ext_vector_type(4)));

// exact 3-plane fp16 split: x == (float)p1 + (float)p2 + (float)p3 for normal-range x
__device__ __forceinline__ void split3(float x, _Float16& p1, _Float16& p2, _Float16& p3) {
  p1 = (_Float16)x;
  float r = x - (float)p1;
  p2 = (_Float16)r;
  float r2 = r - (float)p2;
  p3 = (_Float16)r2;
}

__device__ __forceinline__ float gelu_tanh(float v) {
  float x3 = v * v * v;
  return 0.5f * v * (1.0f + tanhf(0.7978845608028654f * (v + 0.044715f * x3)));
}

// ---------------- embed: h = [x | y] @ W_emb + b_emb (f64 accum) ----------------
__global__ __launch_bounds__(256) void embed_kernel(
    const float* __restrict__ px, const float* __restrict__ py,
    const float* __restrict__ fx, const float* __restrict__ We,
    const float* __restrict__ be, float* __restrict__ h)
{
  int i = blockIdx.x * 256 + threadIdx.x;       // over B*S*D
  int d  = i & 511;
  int bs = i >> 9;                               // b*S + s
  int s  = bs & (Sc - 1);
  int b  = bs >> 11;
  float x[7];
  if (s < SPc) {
    int r = b * SPc + s;
#pragma unroll
    for (int t = 0; t < 6; ++t) x[t] = px[r * 6 + t];
    x[6] = py[r];
  } else {
    int r = b * SFc + (s - SPc);
#pragma unroll
    for (int t = 0; t < 6; ++t) x[t] = fx[r * 6 + t];
    x[6] = py[b * SPc + SPc - 1];                // last observed y, repeated
  }
  double a = (double)be[d];
#pragma unroll
  for (int t = 0; t < 7; ++t) a = fma((double)x[t], (double)We[t * Dc + d], a);
  h[i] = (float)a;
}

// ---------------- row LayerNorm (D=512, block=256), f64 reduction ----------------
__global__ __launch_bounds__(256) void ln_kernel(
    const float* __restrict__ x, const float* __restrict__ g,
    const float* __restrict__ bb, float* __restrict__ o)
{
  int row = blockIdx.x;
  const float* xr = x + (size_t)row * Dc;
  float* orow = o + (size_t)row * Dc;
  int tid = threadIdx.x;
  float v0 = xr[tid], v1 = xr[tid + 256];
  double s = (double)v0 + (double)v1;
  double sq = (double)v0 * v0 + (double)v1 * v1;
  __shared__ double ra[4], rb[4];
  int lane = tid & 63, w = tid >> 6;
#pragma unroll
  for (int off = 32; off; off >>= 1) { s += __shfl_down(s, off); sq += __shfl_down(sq, off); }
  if (lane == 0) { ra[w] = s; rb[w] = sq; }
  __syncthreads();
  s  = ra[0] + ra[1] + ra[2] + ra[3];
  sq = rb[0] + rb[1] + rb[2] + rb[3];
  double m   = s * (1.0 / Dc);
  double var = sq * (1.0 / Dc) - m * m;
  double rs  = 1.0 / sqrt(var + 1e-5);
  orow[tid]       = (float)(((double)v0 - m) * rs * (double)g[tid]       + (double)bb[tid]);
  orow[tid + 256] = (float)(((double)v1 - m) * rs * (double)g[tid + 256] + (double)bb[tid + 256]);
}

// ---------------- f64 MFMA GEMM with runtime C/D-layout probe ----------------
// C(MxN) = A(MxK) @ B(KxN) via v_mfma_f64_16x16x4_f64 (f64-exact accumulation,
// same numerics class as the R2 f64 VALU GEMM that passed).
// A/B lane mapping (1 elem/lane, 16x16 shape): A row = lane%16, k = lane/16;
// B col = lane%16, k = lane/16. The D reg->(row,col) mapping is self-calibrated
// at runtime: probe A[i][k]=d(k,0)+d(k,1)*i, B[k][j]=d(k,0)*j/16+d(k,1)
// => D[i][j] = i + j/16, exactly decodable in f64.
// EP 0: C = acc   1: C += acc   2: C = gelu(acc+bias)   3: C += acc+bias
template<int EP>
__global__ __launch_bounds__(256) void gemm_f64(
    const float* __restrict__ Af, const float* __restrict__ Bf,
    const float* __restrict__ bias, float* __restrict__ C,
    int N, int K)
{
  __shared__ float As[16][132];   // [k][m], padded (2-way max bank alias)
  __shared__ float Bs[16][132];   // [k][n]
  const int tid = threadIdx.x;
  const int nbn = N >> 7;
  const int bm = blockIdx.x / nbn, bn = blockIdx.x % nbn;
  const int m0 = bm << 7, n0 = bn << 7;
  const int wave = tid >> 6, lane = tid & 63;
  const int wm = wave >> 1, wn = wave & 1;
  const int lr = lane & 15, lq = lane >> 4;

  // ---- runtime D-layout probe (one MFMA) ----
  double pa = (lq == 0) ? 1.0 : (lq == 1) ? (double)lr : 0.0;
  double pb = (lq == 0) ? (double)lr * 0.0625 : (lq == 1) ? 1.0 : 0.0;
  f64x4 pd = (f64x4){0.0, 0.0, 0.0, 0.0};
  pd = __builtin_amdgcn_mfma_f64_16x16x4f64(pa, pb, pd, 0, 0, 0);
  int drow[4], dcol[4];
#pragma unroll
  for (int r = 0; r < 4; ++r) {
    double v = pd[r];
    int i = (int)v;                        // exact: v = i + j/16
    int j = (int)((v - (double)i) * 16.0 + 0.5);
    drow[r] = i; dcol[r] = j;
  }

  f64x4 acc[4][4];
#pragma unroll
  for (int i = 0; i < 4; ++i)
#pragma unroll
    for (int j = 0; j < 4; ++j)
      acc[i][j] = (f64x4){0.0, 0.0, 0.0, 0.0};

  for (int kt = 0; kt < K; kt += 16) {
    __syncthreads();                       // previous tile's reads done
#pragma unroll
    for (int h2 = 0; h2 < 2; ++h2) {
      int fi = h2 * 256 + tid;             // 512 float4 per operand tile
      int m  = fi >> 2, kc = (fi & 3) << 2;
      float4 va = *(const float4*)&Af[(size_t)(m0 + m) * K + kt + kc];
      As[kc][m] = va.x; As[kc + 1][m] = va.y; As[kc + 2][m] = va.z; As[kc + 3][m] = va.w;
      int kb2 = fi >> 5, c4 = (fi & 31) << 2;
      *(float4*)&Bs[kb2][c4] = *(const float4*)&Bf[(size_t)(kt + kb2) * N + n0 + c4];
    }
    __syncthreads();
#pragma unroll
    for (int ks = 0; ks < 4; ++ks) {
      double a[4], b[4];
#pragma unroll
      for (int mf = 0; mf < 4; ++mf)
        a[mf] = (double)As[ks * 4 + lq][wm * 64 + mf * 16 + lr];  // A[row=lr][k=lq]
#pragma unroll
      for (int nf = 0; nf < 4; ++nf)
        b[nf] = (double)Bs[ks * 4 + lq][wn * 64 + nf * 16 + lr];  // B[k=lq][col=lr]
#pragma unroll
      for (int mf = 0; mf < 4; ++mf)
#pragma unroll
        for (int nf = 0; nf < 4; ++nf)
          acc[mf][nf] = __builtin_amdgcn_mfma_f64_16x16x4f64(a[mf], b[nf], acc[mf][nf], 0, 0, 0);
    }
  }

#pragma unroll
  for (int mf = 0; mf < 4; ++mf)
#pragma unroll
    for (int nf = 0; nf < 4; ++nf) {
#pragma unroll
      for (int r = 0; r < 4; ++r) {
        int row = m0 + wm * 64 + mf * 16 + drow[r];   // probed mapping
        int col = n0 + wn * 64 + nf * 16 + dcol[r];
        double vd = acc[mf][nf][r];
        size_t o = (size_t)row * N + col;
        if (EP == 0) {
          C[o] = (float)vd;
        } else if (EP == 1) {
          C[o] += (float)vd;
        } else if (EP == 2) {
          vd += (double)bias[col];
          C[o] = gelu_tanh((float)vd);
        } else {
          vd += (double)bias[col];
          C[o] += (float)vd;
        }
      }
    }
}

// ---------------- weight split+transpose: W[K,N] f32 -> P1,P2,P3 [N,K] fp16 ----------------
__global__ __launch_bounds__(256) void splitB3(
    const float* __restrict__ Wm, _Float16* __restrict__ P1,
    _Float16* __restrict__ P2, _Float16* __restrict__ P3, int K, int N)
{
  __shared__ float tile[64][65];
  int tid = threadIdx.x;
  int nbk = K >> 6;
  int bk = blockIdx.x % nbk, bnn = blockIdx.x / nbk;
  int k0 = bk * 64, n0 = bnn * 64;
  int tc = tid & 63, tr = tid >> 6;
#pragma unroll
  for (int i = 0; i < 16; ++i) {
    int k = i * 4 + tr;
    tile[k][tc] = Wm[(size_t)(k0 + k) * N + n0 + tc];
  }
  __syncthreads();
#pragma unroll
  for (int i = 0; i < 16; ++i) {
    int n = i * 4 + tr;
    float x = tile[tc][n];                    // tc = k-local
    _Float16 p1, p2, p3;
    split3(x, p1, p2, p3);
    size_t o = (size_t)(n0 + n) * K + k0 + tc;
    P1[o] = p1; P2[o] = p2; P3[o] = p3;
  }
}

// ---------------- fast fp16x3 MFMA GEMM (layer-3 post-topk value paths only) ----------------
template<int EP>
__global__ __launch_bounds__(256) void gemm3p(
    const float* __restrict__ Af,
    const _Float16* __restrict__ B1, const _Float16* __restrict__ B2,
    const _Float16* __restrict__ B3,
    const float* __restrict__ bias, float* __restrict__ C,
    int N, int K)
{
  __shared__ _Float16 Al[3][128][40];
  __shared__ _Float16 Bl[3][64][40];
  const int tid = threadIdx.x;
  const int nbn = N >> 6;
  const int bm = blockIdx.x / nbn, bn = blockIdx.x % nbn;
  const int m0 = bm << 7, n0 = bn << 6;
  const int wave = tid >> 6, lane = tid & 63;
  const int wm = wave >> 1, wn = wave & 1;
  const int lr = lane & 15, lq = lane >> 4;

  double acc[4][2][4];
#pragma unroll
  for (int i = 0; i < 4; ++i)
#pragma unroll
    for (int j = 0; j < 2; ++j)
#pragma unroll
      for (int r = 0; r < 4; ++r) acc[i][j][r] = 0.0;

  f32x4 apf[4];
  half8 bpf[3];
  const int ar = tid >> 3, ac = (tid & 7) * 4;
  const int bnr = tid >> 2, bkc = (tid & 3) * 8;

  auto load_pf = [&](int k0) {
#pragma unroll
    for (int i = 0; i < 4; ++i)
      apf[i] = *(const f32x4*)&Af[(size_t)(m0 + i * 32 + ar) * K + k0 + ac];
    size_t ob = (size_t)(n0 + bnr) * K + k0 + bkc;
    bpf[0] = *(const half8*)&B1[ob];
    bpf[1] = *(const half8*)&B2[ob];
    bpf[2] = *(const half8*)&B3[ob];
  };
  auto write_lds = [&]() {
#pragma unroll
    for (int i = 0; i < 4; ++i) {
      half4 h1, h2, h3;
#pragma unroll
      for (int j = 0; j < 4; ++j) {
        _Float16 p1, p2, p3;
        split3(apf[i][j], p1, p2, p3);
        h1[j] = p1; h2[j] = p2; h3[j] = p3;
      }
      int row = i * 32 + ar;
      *(half4*)&Al[0][row][ac] = h1;
      *(half4*)&Al[1][row][ac] = h2;
      *(half4*)&Al[2][row][ac] = h3;
    }
    *(half8*)&Bl[0][bnr][bkc] = bpf[0];
    *(half8*)&Bl[1][bnr][bkc] = bpf[1];
    *(half8*)&Bl[2][bnr][bkc] = bpf[2];
  };

  load_pf(0);
  write_lds();
  __syncthreads();

  const int nt = K >> 5;
  for (int t = 0; t < nt; ++t) {
    if (t + 1 < nt) load_pf((t + 1) << 5);

    half8 a1[4], a2[4], a3[4], b1f[2], b2f[2], b3f[2];
#pragma unroll
    for (int mf = 0; mf < 4; ++mf) {
      int row = wm * 64 + mf * 16 + lr;
      a1[mf] = *(const half8*)&Al[0][row][lq * 8];
      a2[mf] = *(const half8*)&Al[1][row][lq * 8];
      a3[mf] = *(const half8*)&Al[2][row][lq * 8];
    }
#pragma unroll
    for (int nf = 0; nf < 2; ++nf) {
      int row = wn * 32 + nf * 16 + lr;
      b1f[nf] = *(const half8*)&Bl[0][row][lq * 8];
      b2f[nf] = *(const half8*)&Bl[1][row][lq * 8];
      b3f[nf] = *(const half8*)&Bl[2][row][lq * 8];
    }
#pragma unroll
    for (int mf = 0; mf < 4; ++mf)
#pragma unroll
      for (int nf = 0; nf < 2; ++nf) {
        f32x4 t0 = (f32x4){0.f, 0.f, 0.f, 0.f};
        t0 = __builtin_amdgcn_mfma_f32_16x16x32_f16(a3[mf], b1f[nf], t0, 0, 0, 0);
        t0 = __builtin_amdgcn_mfma_f32_16x16x32_f16(a2[mf], b2f[nf], t0, 0, 0, 0);
        t0 = __builtin_amdgcn_mfma_f32_16x16x32_f16(a1[mf], b3f[nf], t0, 0, 0, 0);
        t0 = __builtin_amdgcn_mfma_f32_16x16x32_f16(a2[mf], b1f[nf], t0, 0, 0, 0);
        t0 = __builtin_amdgcn_mfma_f32_16x16x32_f16(a1[mf], b2f[nf], t0, 0, 0, 0);
        t0 = __builtin_amdgcn_mfma_f32_16x16x32_f16(a1[mf], b1f[nf], t0, 0, 0, 0);
#pragma unroll
        for (int r = 0; r < 4; ++r) acc[mf][nf][r] += (double)t0[r];
      }

    __syncthreads();
    if (t + 1 < nt) {
      write_lds();
      __syncthreads();
    }
  }

#pragma unroll
  for (int mf = 0; mf < 4; ++mf)
#pragma unroll
    for (int nf = 0; nf < 2; ++nf) {
#pragma unroll
      for (int r = 0; r < 4; ++r) {
        int row = m0 + wm * 64 + mf * 16 + lq * 4 + r;
        int col = n0 + wn * 32 + nf * 16 + lr;
        double vd = acc[mf][nf][r];
        size_t o = (size_t)row * N + col;
        if (EP == 0) {
          C[o] = (float)vd;
        } else if (EP == 1) {
          C[o] += (float)vd;
        } else if (EP == 2) {
          vd += (double)bias[col];
          C[o] = gelu_tanh((float)vd);
        } else {
          vd += (double)bias[col];
          C[o] += (float)vd;
        }
      }
    }
}

// ---------------- routing scores (f64 accum): sc[b,h,c,s] = normalize(q).means ----------------
__global__ __launch_bounds__(256) void scores_kernel(
    const float* __restrict__ q, const float* __restrict__ means,
    float* __restrict__ sc)
{
  int gw   = blockIdx.x * 4 + (threadIdx.x >> 6);  // (b*S+s)*H + h
  int lane = threadIdx.x & 63;
  int h  = gw & 7;
  int bs = gw >> 3;
  int s  = bs & (Sc - 1);
  int b  = bs >> 11;
  float qv = q[(size_t)bs * Dc + h * DHc + lane];
  double sq = (double)qv * (double)qv;
#pragma unroll
  for (int off = 32; off; off >>= 1) sq += __shfl_xor(sq, off);
  double qn = (double)qv / sqrt(sq + 1e-8);
  double myval = 0.0;
#pragma unroll
  for (int c = 0; c < Cc; ++c) {
    double p = qn * (double)means[(h * Cc + c) * DHc + lane];
#pragma unroll
    for (int off = 32; off; off >>= 1) p += __shfl_xor(p, off);
    if (lane == c) myval = p;
  }
  if (lane < Cc)
    sc[(((size_t)b * Hc + h) * Cc + lane) * Sc + s] = (float)myval;
}

// ---------------- top-128 of 2048 via bitonic sort (descending) ----------------
__global__ __launch_bounds__(256) void topk_kernel(
    const float* __restrict__ sc, int* __restrict__ idx_out)
{
  __shared__ float sv[Sc];
  __shared__ int   si[Sc];
  int base = blockIdx.x * Sc;
  int tid = threadIdx.x;
  for (int i = tid; i < Sc; i += 256) { sv[i] = sc[base + i]; si[i] = i; }
  __syncthreads();
  for (int k = 2; k <= Sc; k <<= 1) {
    for (int j = k >> 1; j > 0; j >>= 1) {
      for (int i = tid; i < Sc; i += 256) {
        int ixj = i ^ j;
        if (ixj > i) {
          bool asc = (i & k) != 0;            // overall descending
          float a = sv[i], b2 = sv[ixj];
          if (asc ? (a > b2) : (a < b2)) {
            sv[i] = b2; sv[ixj] = a;
            int t = si[i]; si[i] = si[ixj]; si[ixj] = t;
          }
        }
      }
      __syncthreads();
    }
  }
  if (tid < Wc) idx_out[blockIdx.x * Wc + tid] = si[tid];
}

// ---------------- within-cluster attention (f64 math) + scatter-add ----------------
__global__ __launch_bounds__(128) void attn_kernel(
    const float* __restrict__ q, const float* __restrict__ k,
    const float* __restrict__ v, const int* __restrict__ iq,
    const int* __restrict__ ik, float* __restrict__ accum,
    float* __restrict__ cnt)
{
  __shared__ float ks[Wc][DHc];
  __shared__ float vs[Wc][DHc];
  __shared__ int iqs[Wc], iks[Wc];
  int blk = blockIdx.x;                 // (b*H + h)*C + c
  int tid = threadIdx.x;
  int bh = blk / Cc;
  int h = bh & 7, b = bh >> 3;
  iqs[tid] = iq[blk * Wc + tid];
  iks[tid] = ik[blk * Wc + tid];
  __syncthreads();
  for (int e = tid; e < Wc * DHc; e += 128) {
    int j = e >> 6, d = e & 63;
    size_t off = ((size_t)b * Sc + iks[j]) * Dc + h * DHc + d;
    ks[j][d] = k[off];
    vs[j][d] = v[off];
  }
  __syncthreads();

  size_t qoff = ((size_t)b * Sc + iqs[tid]) * Dc + h * DHc;
  float qr[DHc];
  const float4* q4 = (const float4*)(q + qoff);
#pragma unroll
  for (int d4 = 0; d4 < 16; ++d4) {
    float4 t = q4[d4];
    qr[4 * d4] = t.x; qr[4 * d4 + 1] = t.y; qr[4 * d4 + 2] = t.z; qr[4 * d4 + 3] = t.w;
  }
  double m = -1e300, lsum = 0.0;
  double acc[DHc];
#pragma unroll
  for (int d = 0; d < DHc; ++d) acc[d] = 0.0;

  for (int j = 0; j < Wc; ++j) {
    const float* krow = ks[j];
    double s = 0.0;
#pragma unroll
    for (int d = 0; d < DHc; ++d)
      s = fma((double)qr[d], (double)krow[d], s);
    s *= 0.125;                          // DH^-0.5
    double mn = fmax(m, s);
    double scale = exp(m - mn);
    double p = exp(s - mn);
    lsum = lsum * scale + p;
    const float* vrow = vs[j];
#pragma unroll
    for (int d = 0; d < DHc; ++d)
      acc[d] = fma(acc[d], scale, p * (double)vrow[d]);
    m = mn;
  }
  double inv = 1.0 / lsum;
  float* arow = accum + qoff;
#pragma unroll
  for (int d = 0; d < DHc; ++d) atomicAdd(&arow[d], (float)(acc[d] * inv));
  atomicAdd(&cnt[((size_t)b * Sc + iqs[tid]) * Hc + h], 1.0f);
}

// ---------------- divide by routing count ----------------
__global__ __launch_bounds__(256) void div_kernel(
    float* __restrict__ accum, const float* __restrict__ cnt)
{
  size_t i = (size_t)blockIdx.x * 256 + threadIdx.x;   // over B*S*D
  float c = cnt[i >> 6];                               // (b*S+s)*H + h
  accum[i] /= fmaxf(c, 1.0f);
}

// ---------------- final LN + heads (only future half), f64 ----------------
__global__ __launch_bounds__(256) void final_kernel(
    const float* __restrict__ h, const float* __restrict__ g,
    const float* __restrict__ be, const float* __restrict__ wm,
    const float* __restrict__ bm, const float* __restrict__ wsd,
    const float* __restrict__ bsd, float* __restrict__ out)
{
  int blk = blockIdx.x;                   // b*SF + sf
  int b = blk >> 10, sf = blk & 1023;
  const float* hr = h + ((size_t)b * Sc + SPc + sf) * Dc;
  int tid = threadIdx.x;
  float v0 = hr[tid], v1 = hr[tid + 256];
  double s = (double)v0 + (double)v1;
  double sq = (double)v0 * v0 + (double)v1 * v1;
  __shared__ double ra[4], rb[4];
  int lane = tid & 63, w = tid >> 6;
#pragma unroll
  for (int off = 32; off; off >>= 1) { s += __shfl_down(s, off); sq += __shfl_down(sq, off); }
  if (lane == 0) { ra[w] = s; rb[w] = sq; }
  __syncthreads();
  s  = ra[0] + ra[1] + ra[2] + ra[3];
  sq = rb[0] + rb[1] + rb[2] + rb[3];
  double m   = s * (1.0 / Dc);
  double var = sq * (1.0 / Dc) - m * m;
  double rs  = 1.0 / sqrt(var + 1e-5);
  double n0 = ((double)v0 - m) * rs * (double)g[tid]       + (double)be[tid];
  double n1 = ((double)v1 - m) * rs * (double)g[tid + 256] + (double)be[tid + 256];
  double d1 = n0 * (double)wm[tid]  + n1 * (double)wm[tid + 256];
  double d2 = n0 * (double)wsd[tid] + n1 * (double)wsd[tid + 256];
  __syncthreads();
#pragma unroll
  for (int off = 32; off; off >>= 1) { d1 += __shfl_down(d1, off); d2 += __shfl_down(d2, off); }
  if (lane == 0) { ra[w] = d1; rb[w] = d2; }
  __syncthreads();
  if (tid == 0) {
    double mean = ra[0] + ra[1] + ra[2] + ra[3] + (double)bm[0];
    double ls   = rb[0] + rb[1] + rb[2] + rb[3] + (double)bsd[0];
    double sp = fmax(ls, 0.0) + log1p(exp(-fabs(ls)));   // softplus, stable
    out[blk] = (float)mean;
    out[Bc * SFc + blk] = (float)(0.01 + 0.99 * sp);
  }
}

// ---------------- host orchestration ----------------
extern "C" void kernel_launch(void* const* d_in, const int* in_sizes, int n_in,
                              void* d_out, int out_size, void* d_ws, size_t ws_size,
                              hipStream_t stream) {
  (void)in_sizes; (void)n_in; (void)out_size; (void)ws_size;
  const float* past_x   = (const float*)d_in[0];
  const float* past_y   = (const float*)d_in[1];
  const float* future_x = (const float*)d_in[2];
  const float* W_emb    = (const float*)d_in[3];
  const float* b_emb    = (const float*)d_in[4];
  const float* ln1_g    = (const float*)d_in[5];
  const float* ln1_b    = (const float*)d_in[6];
  const float* Wq       = (const float*)d_in[7];
  const float* Wk       = (const float*)d_in[8];
  const float* Wv       = (const float*)d_in[9];
  const float* Wo       = (const float*)d_in[10];
  const float* means    = (const float*)d_in[11];
  const float* ln2_g    = (const float*)d_in[12];
  const float* ln2_b    = (const float*)d_in[13];
  const float* W1       = (const float*)d_in[14];
  const float* b1       = (const float*)d_in[15];
  const float* W2       = (const float*)d_in[16];
  const float* b2       = (const float*)d_in[17];
  const float* lnf_g    = (const float*)d_in[18];
  const float* lnf_b    = (const float*)d_in[19];
  const float* W_mean   = (const float*)d_in[20];
  const float* b_mean   = (const float*)d_in[21];
  const float* W_std    = (const float*)d_in[22];
  const float* b_std    = (const float*)d_in[23];

  const size_t BSD = (size_t)Bc * Sc * Dc;        // 8.39M floats
  float* h     = (float*)d_ws;                    // [BSD]
  float* R1    = h + BSD;                         // ln output buffer
  float* qb    = h + 2 * BSD;
  float* kb    = h + 3 * BSD;
  float* vb    = h + 4 * BSD;
  float* accum = h + 5 * BSD;                     // attn scatter target
  float* mid   = qb;                              // f32 [Mrows*FFc] reuses qb..accum (dead by FFN)
  float* aux   = h + 6 * BSD;
  float* scq   = aux;                             // 2,097,152 f
  float* sck   = aux + 2097152;                   // 2,097,152 f
  int*   iq    = (int*)(aux + 4194304);           // 262,144 i
  int*   ik    = iq + 262144;                     // 262,144 i
  float* cnt   = (float*)(ik + 262144);           // 131,072 f
  // BT fp16 planes alias scq/sck (16 MB region; 3 x 2 MB; used only after topk consumed scores)
  _Float16* BT1 = (_Float16*)scq;
  _Float16* BT2 = BT1 + 1048576;
  _Float16* BT3 = BT2 + 1048576;

  embed_kernel<<<(int)(BSD / 256), 256, 0, stream>>>(past_x, past_y, future_x, W_emb, b_emb, h);

  const int gF64_D  = (Mrows / 128) * (Dc / 128);   // 512 blocks  (N=512)
  const int gF64_FF = (Mrows / 128) * (FFc / 128);  // 2048 blocks (N=2048)
  const int g3p_D   = (Mrows / 128) * (Dc / 64);    // 1024 blocks
  const int g3p_FF  = (Mrows / 128) * (FFc / 64);   // 4096 blocks
  const int tD_D  = (Dc / 64) * (Dc / 64);
  const int tD_FF = (Dc / 64) * (FFc / 64);
  const int tFF_D = (FFc / 64) * (Dc / 64);

  for (int l = 0; l < Lc; ++l) {
    const bool last = (l == Lc - 1);
    ln_kernel<<<Mrows, 256, 0, stream>>>(h, ln1_g + l * Dc, ln1_b + l * Dc, R1);

    // q,k ALWAYS f64 (they feed top-k scores directly)
    gemm_f64<0><<<gF64_D, 256, 0, stream>>>(R1, Wq + (size_t)l * Dc * Dc, nullptr, qb, Dc, Dc);
    gemm_f64<0><<<gF64_D, 256, 0, stream>>>(R1, Wk + (size_t)l * Dc * Dc, nullptr, kb, Dc, Dc);
    // v: f64 for layers 0-2 (feeds later-layer scores via h); fast for last layer
    if (!last) {
      gemm_f64<0><<<gF64_D, 256, 0, stream>>>(R1, Wv + (size_t)l * Dc * Dc, nullptr, vb, Dc, Dc);
    } else {
      splitB3<<<tD_D, 256, 0, stream>>>(Wv + (size_t)l * Dc * Dc, BT1, BT2, BT3, Dc, Dc);
      gemm3p<0><<<g3p_D, 256, 0, stream>>>(R1, BT1, BT2, BT3, nullptr, vb, Dc, Dc);
    }

    const float* mns = means + (size_t)l * Hc * Cc * DHc;
    scores_kernel<<<Bc * Sc * Hc / 4, 256, 0, stream>>>(qb, mns, scq);
    scores_kernel<<<Bc * Sc * Hc / 4, 256, 0, stream>>>(kb, mns, sck);
    topk_kernel<<<Bc * Hc * Cc, 256, 0, stream>>>(scq, iq);
    topk_kernel<<<Bc * Hc * Cc, 256, 0, stream>>>(sck, ik);

    hipMemsetAsync(accum, 0, BSD * sizeof(float), stream);
    hipMemsetAsync(cnt, 0, (size_t)Bc * Sc * Hc * sizeof(float), stream);

    attn_kernel<<<Bc * Hc * Cc, 128, 0, stream>>>(qb, kb, vb, iq, ik, accum, cnt);
    div_kernel<<<(int)(BSD / 256), 256, 0, stream>>>(accum, cnt);

    // Wo: h += attn_out @ Wo
    if (!last) {
      gemm_f64<1><<<gF64_D, 256, 0, stream>>>(accum, Wo + (size_t)l * Dc * Dc, nullptr, h, Dc, Dc);
    } else {
      splitB3<<<tD_D, 256, 0, stream>>>(Wo + (size_t)l * Dc * Dc, BT1, BT2, BT3, Dc, Dc);
      gemm3p<1><<<g3p_D, 256, 0, stream>>>(accum, BT1, BT2, BT3, nullptr, h, Dc, Dc);
    }

    ln_kernel<<<Mrows, 256, 0, stream>>>(h, ln2_g + l * Dc, ln2_b + l * Dc, R1);

    // FFN
    if (!last) {
      gemm_f64<2><<<gF64_FF, 256, 0, stream>>>(R1, W1 + (size_t)l * Dc * FFc,
                                               b1 + (size_t)l * FFc, mid, FFc, Dc);
      gemm_f64<3><<<gF64_D, 256, 0, stream>>>(mid, W2 + (size_t)l * FFc * Dc,
                                              b2 + (size_t)l * Dc, h, Dc, FFc);
    } else {
      splitB3<<<tD_FF, 256, 0, stream>>>(W1 + (size_t)l * Dc * FFc, BT1, BT2, BT3, Dc, FFc);
      gemm3p<2><<<g3p_FF, 256, 0, stream>>>(R1, BT1, BT2, BT3, b1 + (size_t)l * FFc, mid, FFc, Dc);
      splitB3<<<tFF_D, 256, 0, stream>>>(W2 + (size_t)l * FFc * Dc, BT1, BT2, BT3, FFc, Dc);
      gemm3p<3><<<g3p_D, 256, 0, stream>>>(mid, BT1, BT2, BT3, b2 + (size_t)l * Dc, h, Dc, FFc);
    }
  }

  final_kernel<<<Bc * SFc, 256, 0, stream>>>(h, lnf_g, lnf_b, W_mean, b_mean,
                                             W_std, b_std, (float*)d_out);
}